// Round 3
// baseline (300.732 us; speedup 1.0000x reference)
//
#include <hip/hip_runtime.h>
#include <stdint.h>

#define NT1  256
#define NT2  256
#define KTOP 100
#define CAPC 256     // candidate cap after radix narrowing
#define CAPP 2304    // compacted local-maxima capacity (mean ~1850, sd ~40 for this data)
#define Wdim 128
#define Hdim 128
#define HW   (128 * 128)
#define Cdim 80
#define Bdim 16
#define N2   (Cdim * KTOP)

__device__ __forceinline__ bool precedes(float av, uint32_t ai, float bv, uint32_t bi) {
    // "a before b" in top_k order: larger value first; tie -> smaller index first
    return (av > bv) || (av == bv && ai < bi);
}

// packed key: larger key == earlier in top_k order (value desc, index asc)
__device__ __forceinline__ uint64_t pack_key(float v, uint32_t idx) {
    return ((uint64_t)__float_as_uint(v) << 32) | (uint32_t)(~idx);
}

// wave-aggregated histogram add: one LDS atomic per distinct bin per wave
__device__ __forceinline__ void hist_add_agg(bool pred, uint32_t bin, uint32_t* hist) {
    unsigned long long valid = __ballot(pred);
    while (valid) {
        int leader = __ffsll(valid) - 1;
        uint32_t lbin = (uint32_t)__shfl((int)bin, leader);
        unsigned long long same = __ballot(pred && (bin == lbin));
        if ((int)(threadIdx.x & 63) == leader)
            atomicAdd(&hist[lbin], (uint32_t)__popcll(same));
        valid &= ~same;
    }
}

// ---------------------------------------------------------------------------
// Kernel 1: per-(b,c) 3x3 NMS (rolling vertical window, shfl horizontal)
//           + compact maxima as packed keys + radix-select + rank output
// ---------------------------------------------------------------------------
__global__ __launch_bounds__(NT1, 7)
void nms_topk_kernel(const float* __restrict__ heat,
                     float* __restrict__ scores_ws,
                     int* __restrict__ inds_ws)
{
    __shared__ uint64_t pk[CAPP];     // 18 KB
    __shared__ uint32_t hist[256];
    __shared__ uint64_t ck[CAPC];
    __shared__ uint32_t wsum[4];
    __shared__ uint32_t scal[8];

    const int tid  = threadIdx.x;
    const int lane = tid & 63;
    const int wid  = tid >> 6;
    const int bc   = blockIdx.x;
    const float*  plane  = heat + (size_t)bc * HW;
    const float4* plane4 = (const float4*)plane;

    if (tid == 0) scal[5] = 0;
    __syncthreads();

    // ---- NMS: each thread owns a 16-row x 4-col band; rows loaded once ----
    {
        const int c    = tid & 31;      // float4 column 0..31
        const int band = tid >> 5;      // 0..7
        const int r0   = band * 16;
        float4 cur  = plane4[r0 * 32 + c];
        float4 prev = (r0 > 0) ? plane4[(r0 - 1) * 32 + c] : cur;
        #pragma unroll
        for (int rr = 0; rr < 16; ++rr) {
            const int r = r0 + rr;
            float4 next = (r < Hdim - 1) ? plane4[(r + 1) * 32 + c] : cur;
            float vm0 = fmaxf(cur.x, fmaxf(prev.x, next.x));
            float vm1 = fmaxf(cur.y, fmaxf(prev.y, next.y));
            float vm2 = fmaxf(cur.z, fmaxf(prev.z, next.z));
            float vm3 = fmaxf(cur.w, fmaxf(prev.w, next.w));
            float vl = __shfl_up(vm3, 1);    // same-row left neighbor f4 (lanes 0..31 / 32..63 = one row each)
            float vr = __shfl_down(vm0, 1);
            bool has_l = (c != 0);
            bool has_r = (c != 31);
            float h0 = fmaxf(vm0, vm1); if (has_l) h0 = fmaxf(h0, vl);
            float h1 = fmaxf(vm0, fmaxf(vm1, vm2));
            float h2 = fmaxf(vm1, fmaxf(vm2, vm3));
            float h3 = fmaxf(vm2, vm3); if (has_r) h3 = fmaxf(h3, vr);
            bool k0 = (h0 == cur.x) && (cur.x > 0.0f);
            bool k1 = (h1 == cur.y) && (cur.y > 0.0f);
            bool k2 = (h2 == cur.z) && (cur.z > 0.0f);
            bool k3 = (h3 == cur.w) && (cur.w > 0.0f);
            int nk = (int)k0 + (int)k1 + (int)k2 + (int)k3;
            if (nk) {
                uint32_t pos = atomicAdd(&scal[5], (uint32_t)nk);
                uint32_t p = (uint32_t)((r * 32 + c) << 2);
                if (k0 && pos < CAPP) pk[pos++] = pack_key(cur.x, p + 0);
                if (k1 && pos < CAPP) pk[pos++] = pack_key(cur.y, p + 1);
                if (k2 && pos < CAPP) pk[pos++] = pack_key(cur.z, p + 2);
                if (k3 && pos < CAPP) pk[pos++] = pack_key(cur.w, p + 3);
            }
            prev = cur; cur = next;
        }
    }
    __syncthreads();
    const uint32_t n = scal[5];
    bool ok = (n >= KTOP) && (n <= CAPP);

    uint64_t prefix = 0, kmask = 0;
    uint32_t rank_rem = KTOP, cnt_gt = 0;

    if (ok) {
        bool solved = false;
        for (int lev = 0; lev < 4 && !solved; ++lev) {
            const int shift = 55 - 8 * lev;
            hist[tid] = 0;
            __syncthreads();
            for (uint32_t base = 0; base < n; base += NT1) {
                uint32_t i = base + tid;
                bool in = (i < n);
                uint64_t k = in ? pk[i] : 0;
                bool pred = in && ((k & kmask) == prefix);
                uint32_t bin = (uint32_t)(k >> shift) & 0xFFu;
                hist_add_agg(pred, bin, hist);
            }
            __syncthreads();
            int bin = 255 - tid;
            uint32_t h = hist[bin];
            uint32_t s = h;
            for (int d = 1; d < 64; d <<= 1) {
                uint32_t nn = __shfl_up(s, d);
                if (lane >= d) s += nn;
            }
            if (lane == 63) wsum[wid] = s;
            __syncthreads();
            uint32_t off = 0;
            for (int w2 = 0; w2 < wid; ++w2) off += wsum[w2];
            s += off;                  // count of keys in bins >= bin (within prefix)
            uint32_t s_ex = s - h;     // count in bins > bin
            if (s_ex < rank_rem && rank_rem <= s) {
                scal[0] = (uint32_t)bin; scal[1] = s_ex; scal[2] = h;
            }
            __syncthreads();
            prefix  |= (uint64_t)scal[0] << shift;
            kmask   |= (uint64_t)0xFFu << shift;
            cnt_gt  += scal[1];
            rank_rem -= scal[1];
            solved = (cnt_gt + scal[2] <= CAPC);
        }
        ok = solved;
    }

    if (ok) {
        // ---- compact candidates ----
        if (tid == 0) scal[3] = 0;
        __syncthreads();
        for (uint32_t base = 0; base < n; base += NT1) {
            uint32_t i = base + tid;
            if (i < n) {
                uint64_t k = pk[i];
                if ((k & kmask) >= prefix) {
                    uint32_t slot = atomicAdd(&scal[3], 1u);
                    if (slot < CAPC) ck[slot] = k;
                }
            }
        }
        __syncthreads();
        const uint32_t ct = scal[3];
        // ---- barrier-free rank sort (ct <= 256) on packed keys ----
        if (tid < (int)ct) {
            uint64_t mk = ck[tid];
            uint32_t rank = 0;
            for (uint32_t j = 0; j < ct; ++j)
                rank += (ck[j] > mk) ? 1u : 0u;
            if (rank < KTOP) {
                scores_ws[(size_t)bc * KTOP + rank] = __uint_as_float((uint32_t)(mk >> 32));
                inds_ws[(size_t)bc * KTOP + rank]   = (int)~((uint32_t)mk);
            }
        }
    } else {
        // ---- fully-general fallback: iterative extraction w/ NMS recompute ----
        float lastv = __uint_as_float(0x7F800000u);   // +inf sentinel
        uint32_t lasti = 0xFFFFFFFFu;
        for (int it = 0; it < KTOP; ++it) {
            float bv = -1.0f; uint32_t bi = 0xFFFFFFFFu;
            for (int i2 = 0; i2 < HW / NT1; ++i2) {
                int p = tid + NT1 * i2;
                int y = p >> 7, x = p & (Wdim - 1);
                float v = plane[p];
                float hm = v;
                for (int dy = -1; dy <= 1; ++dy)
                    for (int dx = -1; dx <= 1; ++dx) {
                        int yy = y + dy, xx = x + dx;
                        if (yy >= 0 && yy < Hdim && xx >= 0 && xx < Wdim)
                            hm = fmaxf(hm, plane[yy * Wdim + xx]);
                    }
                float nv = (hm == v) ? v : 0.0f;
                if (precedes(lastv, lasti, nv, (uint32_t)p) &&
                    precedes(nv, (uint32_t)p, bv, bi)) { bv = nv; bi = (uint32_t)p; }
            }
            for (int d = 32; d > 0; d >>= 1) {
                float    ov = __shfl_xor(bv, d);
                uint32_t oi = __shfl_xor(bi, d);
                if (precedes(ov, oi, bv, bi)) { bv = ov; bi = oi; }
            }
            if (lane == 0) { hist[wid] = __float_as_uint(bv); hist[4 + wid] = bi; }
            __syncthreads();
            if (tid == 0) {
                float gv = __uint_as_float(hist[0]); uint32_t gi = hist[4];
                for (int w2 = 1; w2 < 4; ++w2) {
                    float    ov = __uint_as_float(hist[w2]);
                    uint32_t oi = hist[4 + w2];
                    if (precedes(ov, oi, gv, gi)) { gv = ov; gi = oi; }
                }
                scores_ws[(size_t)bc * KTOP + it] = gv;
                inds_ws[(size_t)bc * KTOP + it]   = (int)gi;
                scal[6] = __float_as_uint(gv); scal[7] = gi;
            }
            __syncthreads();
            lastv = __uint_as_float(scal[6]); lasti = scal[7];
            __syncthreads();
        }
    }
}

// ---------------------------------------------------------------------------
// Kernel 2: per-batch top-100 over C*K=8000 + gather + bbox epilogue
// ---------------------------------------------------------------------------
__global__ __launch_bounds__(NT2)
void global_topk_kernel(const float* __restrict__ scores_ws,
                        const int* __restrict__ inds_ws,
                        const float* __restrict__ wh,
                        const float* __restrict__ reg,
                        float* __restrict__ out)
{
    __shared__ float    vals[N2];     // 31.25 KB
    __shared__ uint32_t hist[256];
    __shared__ uint64_t ck[CAPC];
    __shared__ float    sv[KTOP];
    __shared__ uint32_t si[KTOP];
    __shared__ uint32_t wsum[4];
    __shared__ uint32_t scal[8];

    const int tid  = threadIdx.x;
    const int lane = tid & 63;
    const int wid  = tid >> 6;
    const int b    = blockIdx.x;

    if (tid == 0) scal[4] = 0;
    __syncthreads();
    {
        uint32_t c = 0;
        for (int i = tid; i < N2; i += NT2) {
            float v = scores_ws[(size_t)b * N2 + i];
            vals[i] = v;
            if (v > 0.0f) c++;
        }
        atomicAdd(&scal[4], c);
    }
    __syncthreads();
    bool ok = (scal[4] >= KTOP);

    uint64_t prefix = 0, kmask = 0;
    uint32_t rank_rem = KTOP, cnt_gt = 0;

    if (ok) {
        bool solved = false;
        for (int lev = 0; lev < 4 && !solved; ++lev) {
            const int shift = 55 - 8 * lev;
            hist[tid] = 0;
            __syncthreads();
            for (int base = 0; base < N2; base += NT2) {
                int i = base + tid;
                bool in = (i < N2);
                float v = in ? vals[i] : 0.0f;
                bool pos = in && (v > 0.0f);
                uint64_t k = pos ? pack_key(v, (uint32_t)i) : 0;
                bool pred = pos && ((k & kmask) == prefix);
                uint32_t bin = (uint32_t)(k >> shift) & 0xFFu;
                hist_add_agg(pred, bin, hist);
            }
            __syncthreads();
            int bin = 255 - tid;
            uint32_t h = hist[bin];
            uint32_t s = h;
            for (int d = 1; d < 64; d <<= 1) {
                uint32_t nn = __shfl_up(s, d);
                if (lane >= d) s += nn;
            }
            if (lane == 63) wsum[wid] = s;
            __syncthreads();
            uint32_t off = 0;
            for (int w2 = 0; w2 < wid; ++w2) off += wsum[w2];
            s += off;
            uint32_t s_ex = s - h;
            if (s_ex < rank_rem && rank_rem <= s) {
                scal[0] = (uint32_t)bin; scal[1] = s_ex; scal[2] = h;
            }
            __syncthreads();
            prefix  |= (uint64_t)scal[0] << shift;
            kmask   |= (uint64_t)0xFFu << shift;
            cnt_gt  += scal[1];
            rank_rem -= scal[1];
            solved = (cnt_gt + scal[2] <= CAPC);
        }
        ok = solved;
    }

    if (ok) {
        if (tid == 0) scal[3] = 0;
        __syncthreads();
        for (int base = 0; base < N2; base += NT2) {
            int i = base + tid;
            if (i < N2) {
                float v = vals[i];
                if (v > 0.0f) {
                    uint64_t k = pack_key(v, (uint32_t)i);
                    if ((k & kmask) >= prefix) {
                        uint32_t slot = atomicAdd(&scal[3], 1u);
                        if (slot < CAPC) ck[slot] = k;
                    }
                }
            }
        }
        __syncthreads();
        const uint32_t ct = scal[3];
        if (tid < (int)ct) {
            uint64_t mk = ck[tid];
            uint32_t rank = 0;
            for (uint32_t j = 0; j < ct; ++j)
                rank += (ck[j] > mk) ? 1u : 0u;
            if (rank < KTOP) {
                sv[rank] = __uint_as_float((uint32_t)(mk >> 32));
                si[rank] = ~((uint32_t)mk);
            }
        }
        __syncthreads();
    } else {
        // fallback: iterative extraction over vals with -inf marking
        for (int it = 0; it < KTOP; ++it) {
            float bv = -__builtin_inff(); uint32_t bi = 0xFFFFFFFFu;
            for (int i = tid; i < N2; i += NT2) {
                float v = vals[i];
                if (precedes(v, (uint32_t)i, bv, bi)) { bv = v; bi = (uint32_t)i; }
            }
            for (int d = 32; d > 0; d >>= 1) {
                float    ov = __shfl_xor(bv, d);
                uint32_t oi = __shfl_xor(bi, d);
                if (precedes(ov, oi, bv, bi)) { bv = ov; bi = oi; }
            }
            if (lane == 0) { hist[wid] = __float_as_uint(bv); hist[4 + wid] = bi; }
            __syncthreads();
            if (tid == 0) {
                float gv = __uint_as_float(hist[0]); uint32_t gi = hist[4];
                for (int w2 = 1; w2 < 4; ++w2) {
                    float    ov = __uint_as_float(hist[w2]);
                    uint32_t oi = hist[4 + w2];
                    if (precedes(ov, oi, gv, gi)) { gv = ov; gi = oi; }
                }
                sv[it] = gv; si[it] = gi;
                vals[gi] = -__builtin_inff();
            }
            __syncthreads();
        }
    }

    // ---- epilogue: gather + bbox ----
    if (tid < KTOP) {
        float    sc   = sv[tid];
        uint32_t ind2 = si[tid];
        uint32_t cls  = ind2 / KTOP;
        int spatial   = inds_ws[(size_t)b * N2 + ind2];
        float ysf = (float)(spatial >> 7);
        float xsf = (float)(spatial & (Wdim - 1));
        float rx = reg[((size_t)b * 2 + 0) * HW + spatial];
        float ry = reg[((size_t)b * 2 + 1) * HW + spatial];
        float ww = wh [((size_t)b * 2 + 0) * HW + spatial];
        float hh = wh [((size_t)b * 2 + 1) * HW + spatial];
        float xb = xsf + rx, yb = ysf + ry;
        float* o = out + ((size_t)b * KTOP + tid) * 6;
        o[0] = xb - ww * 0.5f;
        o[1] = yb - hh * 0.5f;
        o[2] = xb + ww * 0.5f;
        o[3] = yb + hh * 0.5f;
        o[4] = sc;
        o[5] = (float)cls;
    }
}

extern "C" void kernel_launch(void* const* d_in, const int* in_sizes, int n_in,
                              void* d_out, int out_size, void* d_ws, size_t ws_size,
                              hipStream_t stream)
{
    const float* heat = (const float*)d_in[0];
    const float* wh   = (const float*)d_in[1];
    const float* reg  = (const float*)d_in[2];
    float* out = (float*)d_out;

    float* scores_ws = (float*)d_ws;
    int*   inds_ws   = (int*)((char*)d_ws + (size_t)Bdim * Cdim * KTOP * sizeof(float));

    nms_topk_kernel<<<Bdim * Cdim, NT1, 0, stream>>>(heat, scores_ws, inds_ws);
    global_topk_kernel<<<Bdim, NT2, 0, stream>>>(scores_ws, inds_ws, wh, reg, out);
}

// Round 4
// 166.115 us; speedup vs baseline: 1.8104x; 1.8104x over previous
//
#include <hip/hip_runtime.h>
#include <stdint.h>

#define NT1  256
#define NT2  1024
#define KTOP 100
#define CAPC 256     // candidate cap after radix narrowing
#define CAPP 2304    // compacted local-maxima capacity (mean ~1850 for this data)
#define Wdim 128
#define Hdim 128
#define HW   (128 * 128)
#define Cdim 80
#define Bdim 16
#define N2   (Cdim * KTOP)

__device__ __forceinline__ bool precedes(float av, uint32_t ai, float bv, uint32_t bi) {
    return (av > bv) || (av == bv && ai < bi);
}

// per-plane key: value desc, spatial asc  (values inserted are > 0)
__device__ __forceinline__ uint64_t pack_key(float v, uint32_t idx) {
    return ((uint64_t)__float_as_uint(v) << 32) | (uint32_t)(~idx);
}

// monotonic total-order mapping for float bits
__device__ __forceinline__ uint32_t fmap(float v) {
    uint32_t b = __float_as_uint(v);
    return (b >> 31) ? ~b : (b | 0x80000000u);
}
// global key: (value desc, class asc, spatial asc) in 53 bits
__device__ __forceinline__ uint64_t pack_global(float v, uint32_t cls, uint32_t sp) {
    return ((uint64_t)fmap(v) << 21) | ((~((cls << 14) | sp)) & 0x1FFFFFu);
}

// ---------------------------------------------------------------------------
// Kernel 1: per-(b,c) 3x3 NMS + compact + radix-select top-100 -> global keys
// ---------------------------------------------------------------------------
__global__ __launch_bounds__(NT1, 7)
void nms_topk_kernel(const float* __restrict__ heat,
                     uint64_t* __restrict__ keys_ws)
{
    __shared__ uint64_t pk[CAPP];     // 18 KB
    __shared__ uint32_t hist[256];
    __shared__ uint64_t ck[CAPC];
    __shared__ uint32_t wsum[4];
    __shared__ uint32_t scal[8];

    const int tid  = threadIdx.x;
    const int lane = tid & 63;
    const int wid  = tid >> 6;
    const int bc   = blockIdx.x;
    const uint32_t cls = (uint32_t)(bc % Cdim);
    const float*  plane  = heat + (size_t)bc * HW;
    const float4* plane4 = (const float4*)plane;

    if (tid == 0) scal[5] = 0;
    __syncthreads();

    // ---- NMS: each thread owns a 16-row x 4-col band; rows loaded once ----
    {
        const int c    = tid & 31;      // float4 column 0..31
        const int band = tid >> 5;      // 0..7
        const int r0   = band * 16;
        float4 cur  = plane4[r0 * 32 + c];
        float4 prev = (r0 > 0) ? plane4[(r0 - 1) * 32 + c] : cur;
        #pragma unroll
        for (int rr = 0; rr < 16; ++rr) {
            const int r = r0 + rr;
            float4 next = (r < Hdim - 1) ? plane4[(r + 1) * 32 + c] : cur;
            float vm0 = fmaxf(cur.x, fmaxf(prev.x, next.x));
            float vm1 = fmaxf(cur.y, fmaxf(prev.y, next.y));
            float vm2 = fmaxf(cur.z, fmaxf(prev.z, next.z));
            float vm3 = fmaxf(cur.w, fmaxf(prev.w, next.w));
            float vl = __shfl_up(vm3, 1);    // lanes 0..31 / 32..63 each hold one row
            float vr = __shfl_down(vm0, 1);
            bool has_l = (c != 0);
            bool has_r = (c != 31);
            float h0 = fmaxf(vm0, vm1); if (has_l) h0 = fmaxf(h0, vl);
            float h1 = fmaxf(vm0, fmaxf(vm1, vm2));
            float h2 = fmaxf(vm1, fmaxf(vm2, vm3));
            float h3 = fmaxf(vm2, vm3); if (has_r) h3 = fmaxf(h3, vr);
            bool k0 = (h0 == cur.x) && (cur.x > 0.0f);
            bool k1 = (h1 == cur.y) && (cur.y > 0.0f);
            bool k2 = (h2 == cur.z) && (cur.z > 0.0f);
            bool k3 = (h3 == cur.w) && (cur.w > 0.0f);
            int nk = (int)k0 + (int)k1 + (int)k2 + (int)k3;
            // wave-level prefix sum of nk -> one LDS atomic per wave per row
            int incl = nk;
            #pragma unroll
            for (int d = 1; d < 64; d <<= 1) {
                int t = __shfl_up(incl, d);
                if (lane >= d) incl += t;
            }
            uint32_t wtotal = (uint32_t)__shfl(incl, 63);
            uint32_t base = 0;
            if (lane == 63) base = atomicAdd(&scal[5], wtotal);
            base = (uint32_t)__shfl((int)base, 63);
            uint32_t pos = base + (uint32_t)(incl - nk);
            if (nk) {
                uint32_t p = (uint32_t)((r * 32 + c) << 2);
                if (k0 && pos < CAPP) pk[pos++] = pack_key(cur.x, p + 0);
                if (k1 && pos < CAPP) pk[pos++] = pack_key(cur.y, p + 1);
                if (k2 && pos < CAPP) pk[pos++] = pack_key(cur.z, p + 2);
                if (k3 && pos < CAPP) pk[pos++] = pack_key(cur.w, p + 3);
            }
            prev = cur; cur = next;
        }
    }
    __syncthreads();
    const uint32_t n = scal[5];
    const bool ok = (n >= KTOP) && (n <= CAPP);

    if (ok) {
        uint64_t prefix = 0, kmask = 0;
        uint32_t rank_rem = KTOP, cnt_gt = 0;
        bool solved = false;
        // keys unique (spatial distinct) -> guaranteed solved by shift 7
        #pragma unroll 1
        for (int lev = 0; lev < 7 && !solved; ++lev) {
            const int shift = 55 - 8 * lev;
            hist[tid] = 0;
            __syncthreads();
            for (uint32_t base = 0; base < n; base += NT1) {
                uint32_t i = base + tid;
                if (i < n) {
                    uint64_t k = pk[i];
                    if ((k & kmask) == prefix)
                        atomicAdd(&hist[(uint32_t)(k >> shift) & 0xFFu], 1u);
                }
            }
            __syncthreads();
            int bin = 255 - tid;
            uint32_t h = hist[bin];
            uint32_t s = h;
            for (int d = 1; d < 64; d <<= 1) {
                uint32_t nn = __shfl_up(s, d);
                if (lane >= d) s += nn;
            }
            if (lane == 63) wsum[wid] = s;
            __syncthreads();
            uint32_t off = 0;
            for (int w2 = 0; w2 < wid; ++w2) off += wsum[w2];
            s += off;                  // keys in bins >= bin (within prefix)
            uint32_t s_ex = s - h;     // keys in bins > bin
            if (s_ex < rank_rem && rank_rem <= s) {
                scal[0] = (uint32_t)bin; scal[1] = s_ex; scal[2] = h;
            }
            __syncthreads();
            prefix  |= (uint64_t)scal[0] << shift;
            kmask   |= (uint64_t)0xFFu << shift;
            cnt_gt  += scal[1];
            rank_rem -= scal[1];
            solved = (cnt_gt + scal[2] <= CAPC);
        }
        // ---- compact candidates (ballot-aggregated slot allocation) ----
        if (tid == 0) scal[3] = 0;
        __syncthreads();
        for (uint32_t base = 0; base < n; base += NT1) {
            uint32_t i = base + tid;
            bool pred = false;
            uint64_t k = 0;
            if (i < n) { k = pk[i]; pred = ((k & kmask) >= prefix); }
            unsigned long long m = __ballot(pred);
            uint32_t cnt = (uint32_t)__popcll(m);
            uint32_t before = (uint32_t)__popcll(m & ((1ull << lane) - 1ull));
            uint32_t sbase = 0;
            if (lane == 0 && cnt) sbase = atomicAdd(&scal[3], cnt);
            sbase = (uint32_t)__shfl((int)sbase, 0);
            if (pred) {
                uint32_t slot = sbase + before;
                if (slot < CAPC) ck[slot] = k;
            }
        }
        __syncthreads();
        const uint32_t ct = scal[3];
        // ---- barrier-free rank sort (ct <= 256) ----
        if (tid < (int)ct) {
            uint64_t mk = ck[tid];
            uint32_t rank = 0;
            for (uint32_t j = 0; j < ct; ++j)
                rank += (ck[j] > mk) ? 1u : 0u;
            if (rank < KTOP) {
                float v = __uint_as_float((uint32_t)(mk >> 32));
                uint32_t sp = ~((uint32_t)mk);
                keys_ws[(size_t)bc * KTOP + rank] = pack_global(v, cls, sp);
            }
        }
    } else {
        // ---- fully-general fallback: iterative extraction w/ NMS recompute ----
        float lastv = __uint_as_float(0x7F800000u);
        uint32_t lasti = 0xFFFFFFFFu;
        for (int it = 0; it < KTOP; ++it) {
            float bv = -__builtin_inff(); uint32_t bi = 0xFFFFFFFFu;
            for (int i2 = 0; i2 < HW / NT1; ++i2) {
                int p = tid + NT1 * i2;
                int y = p >> 7, x = p & (Wdim - 1);
                float v = plane[p];
                float hm = v;
                for (int dy = -1; dy <= 1; ++dy)
                    for (int dx = -1; dx <= 1; ++dx) {
                        int yy = y + dy, xx = x + dx;
                        if (yy >= 0 && yy < Hdim && xx >= 0 && xx < Wdim)
                            hm = fmaxf(hm, plane[yy * Wdim + xx]);
                    }
                float nv = (hm == v) ? v : 0.0f;
                if (precedes(lastv, lasti, nv, (uint32_t)p) &&
                    precedes(nv, (uint32_t)p, bv, bi)) { bv = nv; bi = (uint32_t)p; }
            }
            for (int d = 32; d > 0; d >>= 1) {
                float    ov = __shfl_xor(bv, d);
                uint32_t oi = __shfl_xor(bi, d);
                if (precedes(ov, oi, bv, bi)) { bv = ov; bi = oi; }
            }
            if (lane == 0) { hist[wid] = __float_as_uint(bv); hist[4 + wid] = bi; }
            __syncthreads();
            if (tid == 0) {
                float gv = __uint_as_float(hist[0]); uint32_t gi = hist[4];
                for (int w2 = 1; w2 < 4; ++w2) {
                    float    ov = __uint_as_float(hist[w2]);
                    uint32_t oi = hist[4 + w2];
                    if (precedes(ov, oi, gv, gi)) { gv = ov; gi = oi; }
                }
                keys_ws[(size_t)bc * KTOP + it] = pack_global(gv, cls, gi);
                scal[6] = __float_as_uint(gv); scal[7] = gi;
            }
            __syncthreads();
            lastv = __uint_as_float(scal[6]); lasti = scal[7];
            __syncthreads();
        }
    }
}

// ---------------------------------------------------------------------------
// Kernel 2: per-batch top-100 over 8000 unique keys + gather + bbox epilogue
// ---------------------------------------------------------------------------
__global__ __launch_bounds__(NT2)
void global_topk_kernel(const uint64_t* __restrict__ keys_ws,
                        const float* __restrict__ wh,
                        const float* __restrict__ reg,
                        float* __restrict__ out)
{
    __shared__ uint32_t hist[256];
    __shared__ uint64_t ck[CAPC];
    __shared__ uint32_t wsum[4];
    __shared__ uint32_t scal[8];

    const int tid  = threadIdx.x;
    const int lane = tid & 63;
    const int b    = blockIdx.x;
    const uint64_t* kb = keys_ws + (size_t)b * N2;

    // 8 keys per thread, in registers (statically unrolled; only j=7 is guarded)
    uint64_t kk[8];
    #pragma unroll
    for (int j = 0; j < 8; ++j) {
        int i = tid + NT2 * j;
        kk[j] = (j < 7 || tid < (N2 - 7 * NT2)) ? kb[i] : 0;
    }

    uint64_t prefix = 0, kmask = 0;
    uint32_t rank_rem = KTOP, cnt_gt = 0;
    bool solved = false;
    // 53-bit keys, globally unique -> guaranteed solved by shift 5
    #pragma unroll 1
    for (int lev = 0; lev < 6 && !solved; ++lev) {
        const int shift = 45 - 8 * lev;
        if (tid < 256) hist[tid] = 0;
        __syncthreads();
        #pragma unroll
        for (int j = 0; j < 8; ++j) {
            bool valid = (j < 7 || tid < (N2 - 7 * NT2));
            if (valid && (kk[j] & kmask) == prefix)
                atomicAdd(&hist[(uint32_t)(kk[j] >> shift) & 0xFFu], 1u);
        }
        __syncthreads();
        if (tid < 256) {
            int bin = 255 - tid;
            uint32_t h = hist[bin];
            uint32_t s = h;
            for (int d = 1; d < 64; d <<= 1) {
                uint32_t nn = __shfl_up(s, d);
                if (lane >= d) s += nn;
            }
            if (lane == 63) wsum[tid >> 6] = s;
        }
        __syncthreads();
        if (tid < 256) {
            uint32_t h = hist[255 - tid];
            uint32_t s = h;
            for (int d = 1; d < 64; d <<= 1) {
                uint32_t nn = __shfl_up(s, d);
                if (lane >= d) s += nn;
            }
            uint32_t off = 0;
            for (int w2 = 0; w2 < (tid >> 6); ++w2) off += wsum[w2];
            s += off;
            uint32_t s_ex = s - h;
            if (s_ex < rank_rem && rank_rem <= s) {
                scal[0] = (uint32_t)(255 - tid); scal[1] = s_ex; scal[2] = h;
            }
        }
        __syncthreads();
        prefix  |= (uint64_t)scal[0] << shift;
        kmask   |= (uint64_t)0xFFu << shift;
        cnt_gt  += scal[1];
        rank_rem -= scal[1];
        solved = (cnt_gt + scal[2] <= CAPC);
        __syncthreads();
    }

    // ---- compact candidates ----
    if (tid == 0) scal[3] = 0;
    __syncthreads();
    #pragma unroll
    for (int j = 0; j < 8; ++j) {
        bool valid = (j < 7 || tid < (N2 - 7 * NT2));
        bool pred = valid && ((kk[j] & kmask) >= prefix);
        unsigned long long m = __ballot(pred);
        uint32_t cnt = (uint32_t)__popcll(m);
        uint32_t before = (uint32_t)__popcll(m & ((1ull << lane) - 1ull));
        uint32_t sbase = 0;
        if (lane == 0 && cnt) sbase = atomicAdd(&scal[3], cnt);
        sbase = (uint32_t)__shfl((int)sbase, 0);
        if (pred) {
            uint32_t slot = sbase + before;
            if (slot < CAPC) ck[slot] = kk[j];
        }
    }
    __syncthreads();
    const uint32_t ct = scal[3];

    // ---- rank sort + decode + epilogue ----
    if (tid < (int)ct) {
        uint64_t mk = ck[tid];
        uint32_t rank = 0;
        for (uint32_t j = 0; j < ct; ++j)
            rank += (ck[j] > mk) ? 1u : 0u;
        if (rank < KTOP) {
            uint32_t m  = (uint32_t)(mk >> 21);
            uint32_t vb = (m & 0x80000000u) ? (m ^ 0x80000000u) : ~m;
            float sc = __uint_as_float(vb);
            uint32_t low = (~(uint32_t)mk) & 0x1FFFFFu;
            uint32_t cls = low >> 14;
            int spatial  = (int)(low & 0x3FFFu);
            float ysf = (float)(spatial >> 7);
            float xsf = (float)(spatial & (Wdim - 1));
            float rx = reg[((size_t)b * 2 + 0) * HW + spatial];
            float ry = reg[((size_t)b * 2 + 1) * HW + spatial];
            float ww = wh [((size_t)b * 2 + 0) * HW + spatial];
            float hh = wh [((size_t)b * 2 + 1) * HW + spatial];
            float xb = xsf + rx, yb = ysf + ry;
            float* o = out + ((size_t)b * KTOP + rank) * 6;
            o[0] = xb - ww * 0.5f;
            o[1] = yb - hh * 0.5f;
            o[2] = xb + ww * 0.5f;
            o[3] = yb + hh * 0.5f;
            o[4] = sc;
            o[5] = (float)cls;
        }
    }
}

extern "C" void kernel_launch(void* const* d_in, const int* in_sizes, int n_in,
                              void* d_out, int out_size, void* d_ws, size_t ws_size,
                              hipStream_t stream)
{
    const float* heat = (const float*)d_in[0];
    const float* wh   = (const float*)d_in[1];
    const float* reg  = (const float*)d_in[2];
    float* out = (float*)d_out;

    uint64_t* keys_ws = (uint64_t*)d_ws;   // 16*80*100*8B = 1.024 MB

    nms_topk_kernel<<<Bdim * Cdim, NT1, 0, stream>>>(heat, keys_ws);
    global_topk_kernel<<<Bdim, NT2, 0, stream>>>(keys_ws, wh, reg, out);
}

// Round 10
// 155.434 us; speedup vs baseline: 1.9348x; 1.0687x over previous
//
#include <hip/hip_runtime.h>
#include <stdint.h>

#define NT1  256
#define NT2  1024
#define KTOP 100
#define CAPC 256     // candidate cap after radix narrowing
#define CAPP 2304    // compacted local-maxima capacity (mean ~1850 for this data)
#define Wdim 128
#define Hdim 128
#define HW   (128 * 128)
#define Cdim 80
#define Bdim 16
#define N2   (Cdim * KTOP)

__device__ __forceinline__ bool precedes(float av, uint32_t ai, float bv, uint32_t bi) {
    return (av > bv) || (av == bv && ai < bi);
}

// per-plane key: value desc, spatial asc  (values inserted are > 0)
__device__ __forceinline__ uint64_t pack_key(float v, uint32_t idx) {
    return ((uint64_t)__float_as_uint(v) << 32) | (uint32_t)(~idx);
}

// monotonic total-order mapping for float bits
__device__ __forceinline__ uint32_t fmap(float v) {
    uint32_t b = __float_as_uint(v);
    return (b >> 31) ? ~b : (b | 0x80000000u);
}
// global key: (value desc, class asc, spatial asc) in 53 bits
__device__ __forceinline__ uint64_t pack_global(float v, uint32_t cls, uint32_t sp) {
    return ((uint64_t)fmap(v) << 21) | ((~((cls << 14) | sp)) & 0x1FFFFFu);
}

// wave-aggregated histogram add: one LDS atomic per distinct bin per wave.
// Use ONLY for clustered bins (radix level 0 = exponent byte); for spread
// bins plain atomicAdd is cheaper (R3 lesson).
__device__ __forceinline__ void hist_add_agg(bool pred, uint32_t bin, uint32_t* hist) {
    const int lane = (int)(threadIdx.x & 63);
    unsigned long long valid = __ballot(pred);
    while (valid) {
        int leader = __ffsll((unsigned long long)valid) - 1;
        uint32_t lbin = (uint32_t)__shfl((int)bin, leader);
        unsigned long long same = __ballot(pred && (bin == lbin));
        if (lane == leader)
            atomicAdd(&hist[lbin], (uint32_t)__popcll(same));
        valid &= ~same;
    }
}

// ---------------------------------------------------------------------------
// Kernel 1: per-(b,c) 3x3 NMS + compact + radix-select top-100 -> global keys
// ---------------------------------------------------------------------------
__global__ __launch_bounds__(NT1, 7)
void nms_topk_kernel(const float* __restrict__ heat,
                     uint64_t* __restrict__ keys_ws)
{
    __shared__ uint64_t pk[CAPP];     // 18 KB
    __shared__ uint32_t hist[256];
    __shared__ uint64_t ck[CAPC];
    __shared__ uint32_t wsum[4];
    __shared__ uint32_t scal[8];

    const int tid  = threadIdx.x;
    const int lane = tid & 63;
    const int wid  = tid >> 6;
    const int bc   = blockIdx.x;
    const uint32_t cls = (uint32_t)(bc % Cdim);
    const float*  plane  = heat + (size_t)bc * HW;
    const float4* plane4 = (const float4*)plane;

    if (tid == 0) scal[5] = 0;
    __syncthreads();

    // ---- NMS: each thread owns a 16-row x 4-col band; rows loaded once ----
    {
        const int c    = tid & 31;      // float4 column 0..31
        const int band = tid >> 5;      // 0..7
        const int r0   = band * 16;
        float4 cur  = plane4[r0 * 32 + c];
        float4 prev = (r0 > 0) ? plane4[(r0 - 1) * 32 + c] : cur;
        #pragma unroll
        for (int rr = 0; rr < 16; ++rr) {
            const int r = r0 + rr;
            float4 next = (r < Hdim - 1) ? plane4[(r + 1) * 32 + c] : cur;
            float vm0 = fmaxf(cur.x, fmaxf(prev.x, next.x));
            float vm1 = fmaxf(cur.y, fmaxf(prev.y, next.y));
            float vm2 = fmaxf(cur.z, fmaxf(prev.z, next.z));
            float vm3 = fmaxf(cur.w, fmaxf(prev.w, next.w));
            float vl = __shfl_up(vm3, 1);    // lanes 0..31 / 32..63 each hold one row
            float vr = __shfl_down(vm0, 1);
            bool has_l = (c != 0);
            bool has_r = (c != 31);
            float h0 = fmaxf(vm0, vm1); if (has_l) h0 = fmaxf(h0, vl);
            float h1 = fmaxf(vm0, fmaxf(vm1, vm2));
            float h2 = fmaxf(vm1, fmaxf(vm2, vm3));
            float h3 = fmaxf(vm2, vm3); if (has_r) h3 = fmaxf(h3, vr);
            bool k0 = (h0 == cur.x) && (cur.x > 0.0f);
            bool k1 = (h1 == cur.y) && (cur.y > 0.0f);
            bool k2 = (h2 == cur.z) && (cur.z > 0.0f);
            bool k3 = (h3 == cur.w) && (cur.w > 0.0f);
            int nk = (int)k0 + (int)k1 + (int)k2 + (int)k3;
            // wave-level prefix sum of nk -> one LDS atomic per wave per row
            int incl = nk;
            #pragma unroll
            for (int d = 1; d < 64; d <<= 1) {
                int t = __shfl_up(incl, d);
                if (lane >= d) incl += t;
            }
            uint32_t wtotal = (uint32_t)__shfl(incl, 63);
            uint32_t base = 0;
            if (lane == 63) base = atomicAdd(&scal[5], wtotal);
            base = (uint32_t)__shfl((int)base, 63);
            uint32_t pos = base + (uint32_t)(incl - nk);
            if (nk) {
                uint32_t p = (uint32_t)((r * 32 + c) << 2);
                if (k0 && pos < CAPP) pk[pos++] = pack_key(cur.x, p + 0);
                if (k1 && pos < CAPP) pk[pos++] = pack_key(cur.y, p + 1);
                if (k2 && pos < CAPP) pk[pos++] = pack_key(cur.z, p + 2);
                if (k3 && pos < CAPP) pk[pos++] = pack_key(cur.w, p + 3);
            }
            prev = cur; cur = next;
        }
    }
    __syncthreads();
    const uint32_t n = scal[5];
    const bool ok = (n >= KTOP) && (n <= CAPP);

    if (ok) {
        uint64_t prefix = 0, kmask = 0;
        uint32_t rank_rem = KTOP, cnt_gt = 0;
        bool solved = false;
        // keys unique (spatial distinct) -> guaranteed solved by shift 7
        #pragma unroll 1
        for (int lev = 0; lev < 7 && !solved; ++lev) {
            const int shift = 55 - 8 * lev;
            hist[tid] = 0;
            __syncthreads();
            for (uint32_t base = 0; base < n; base += NT1) {
                uint32_t i = base + tid;
                bool in = (i < n);
                uint64_t k = in ? pk[i] : 0;
                uint32_t bin = (uint32_t)(k >> shift) & 0xFFu;
                bool pred = in && ((k & kmask) == prefix);
                if (lev == 0) hist_add_agg(pred, bin, hist);   // clustered bins
                else if (pred) atomicAdd(&hist[bin], 1u);      // spread bins
            }
            __syncthreads();
            int bin = 255 - tid;
            uint32_t h = hist[bin];
            uint32_t s = h;
            for (int d = 1; d < 64; d <<= 1) {
                uint32_t nn = __shfl_up(s, d);
                if (lane >= d) s += nn;
            }
            if (lane == 63) wsum[wid] = s;
            __syncthreads();
            uint32_t off = 0;
            for (int w2 = 0; w2 < wid; ++w2) off += wsum[w2];
            s += off;                  // keys in bins >= bin (within prefix)
            uint32_t s_ex = s - h;     // keys in bins > bin
            if (s_ex < rank_rem && rank_rem <= s) {
                scal[0] = (uint32_t)bin; scal[1] = s_ex; scal[2] = h;
            }
            __syncthreads();
            prefix  |= (uint64_t)scal[0] << shift;
            kmask   |= (uint64_t)0xFFu << shift;
            cnt_gt  += scal[1];
            rank_rem -= scal[1];
            solved = (cnt_gt + scal[2] <= CAPC);
        }
        // ---- compact candidates (ballot-aggregated slot allocation) ----
        if (tid == 0) scal[3] = 0;
        __syncthreads();
        for (uint32_t base = 0; base < n; base += NT1) {
            uint32_t i = base + tid;
            bool pred = false;
            uint64_t k = 0;
            if (i < n) { k = pk[i]; pred = ((k & kmask) >= prefix); }
            unsigned long long m = __ballot(pred);
            uint32_t cnt = (uint32_t)__popcll(m);
            uint32_t before = (uint32_t)__popcll(m & ((1ull << lane) - 1ull));
            uint32_t sbase = 0;
            if (lane == 0 && cnt) sbase = atomicAdd(&scal[3], cnt);
            sbase = (uint32_t)__shfl((int)sbase, 0);
            if (pred) {
                uint32_t slot = sbase + before;
                if (slot < CAPC) ck[slot] = k;
            }
        }
        __syncthreads();
        const uint32_t ct = scal[3];
        // ---- barrier-free rank sort (ct <= 256) ----
        if (tid < (int)ct) {
            uint64_t mk = ck[tid];
            uint32_t rank = 0;
            for (uint32_t j = 0; j < ct; ++j)
                rank += (ck[j] > mk) ? 1u : 0u;
            if (rank < KTOP) {
                float v = __uint_as_float((uint32_t)(mk >> 32));
                uint32_t sp = ~((uint32_t)mk);
                keys_ws[(size_t)bc * KTOP + rank] = pack_global(v, cls, sp);
            }
        }
    } else {
        // ---- fully-general fallback: iterative extraction w/ NMS recompute ----
        float lastv = __uint_as_float(0x7F800000u);
        uint32_t lasti = 0xFFFFFFFFu;
        for (int it = 0; it < KTOP; ++it) {
            float bv = -__builtin_inff(); uint32_t bi = 0xFFFFFFFFu;
            for (int i2 = 0; i2 < HW / NT1; ++i2) {
                int p = tid + NT1 * i2;
                int y = p >> 7, x = p & (Wdim - 1);
                float v = plane[p];
                float hm = v;
                for (int dy = -1; dy <= 1; ++dy)
                    for (int dx = -1; dx <= 1; ++dx) {
                        int yy = y + dy, xx = x + dx;
                        if (yy >= 0 && yy < Hdim && xx >= 0 && xx < Wdim)
                            hm = fmaxf(hm, plane[yy * Wdim + xx]);
                    }
                float nv = (hm == v) ? v : 0.0f;
                if (precedes(lastv, lasti, nv, (uint32_t)p) &&
                    precedes(nv, (uint32_t)p, bv, bi)) { bv = nv; bi = (uint32_t)p; }
            }
            for (int d = 32; d > 0; d >>= 1) {
                float    ov = __shfl_xor(bv, d);
                uint32_t oi = __shfl_xor(bi, d);
                if (precedes(ov, oi, bv, bi)) { bv = ov; bi = oi; }
            }
            if (lane == 0) { hist[wid] = __float_as_uint(bv); hist[4 + wid] = bi; }
            __syncthreads();
            if (tid == 0) {
                float gv = __uint_as_float(hist[0]); uint32_t gi = hist[4];
                for (int w2 = 1; w2 < 4; ++w2) {
                    float    ov = __uint_as_float(hist[w2]);
                    uint32_t oi = hist[4 + w2];
                    if (precedes(ov, oi, gv, gi)) { gv = ov; gi = oi; }
                }
                keys_ws[(size_t)bc * KTOP + it] = pack_global(gv, cls, gi);
                scal[6] = __float_as_uint(gv); scal[7] = gi;
            }
            __syncthreads();
            lastv = __uint_as_float(scal[6]); lasti = scal[7];
            __syncthreads();
        }
    }
}

// ---------------------------------------------------------------------------
// Kernel 2: per-batch top-100 over 8000 unique keys + gather + bbox epilogue
// ---------------------------------------------------------------------------
__global__ __launch_bounds__(NT2)
void global_topk_kernel(const uint64_t* __restrict__ keys_ws,
                        const float* __restrict__ wh,
                        const float* __restrict__ reg,
                        float* __restrict__ out)
{
    __shared__ uint32_t hist[256];
    __shared__ uint64_t ck[CAPC];
    __shared__ uint32_t wsum[4];
    __shared__ uint32_t scal[8];

    const int tid  = threadIdx.x;
    const int lane = tid & 63;
    const int b    = blockIdx.x;
    const uint64_t* kb = keys_ws + (size_t)b * N2;

    // 8 keys per thread, in registers (statically unrolled; only j=7 is guarded)
    uint64_t kk[8];
    #pragma unroll
    for (int j = 0; j < 8; ++j) {
        int i = tid + NT2 * j;
        kk[j] = (j < 7 || tid < (N2 - 7 * NT2)) ? kb[i] : 0;
    }

    uint64_t prefix = 0, kmask = 0;
    uint32_t rank_rem = KTOP, cnt_gt = 0;
    bool solved = false;
    // 53-bit keys, globally unique -> guaranteed solved by shift 5
    #pragma unroll 1
    for (int lev = 0; lev < 6 && !solved; ++lev) {
        const int shift = 45 - 8 * lev;
        if (tid < 256) hist[tid] = 0;
        __syncthreads();
        #pragma unroll
        for (int j = 0; j < 8; ++j) {
            bool valid = (j < 7 || tid < (N2 - 7 * NT2));
            uint32_t bin = (uint32_t)(kk[j] >> shift) & 0xFFu;
            bool pred = valid && ((kk[j] & kmask) == prefix);
            if (lev == 0) hist_add_agg(pred, bin, hist);   // clustered bins
            else if (pred) atomicAdd(&hist[bin], 1u);      // spread bins
        }
        __syncthreads();
        if (tid < 256) {
            int bin = 255 - tid;
            uint32_t h = hist[bin];
            uint32_t s = h;
            for (int d = 1; d < 64; d <<= 1) {
                uint32_t nn = __shfl_up(s, d);
                if (lane >= d) s += nn;
            }
            if (lane == 63) wsum[tid >> 6] = s;
        }
        __syncthreads();
        if (tid < 256) {
            uint32_t h = hist[255 - tid];
            uint32_t s = h;
            for (int d = 1; d < 64; d <<= 1) {
                uint32_t nn = __shfl_up(s, d);
                if (lane >= d) s += nn;
            }
            uint32_t off = 0;
            for (int w2 = 0; w2 < (tid >> 6); ++w2) off += wsum[w2];
            s += off;
            uint32_t s_ex = s - h;
            if (s_ex < rank_rem && rank_rem <= s) {
                scal[0] = (uint32_t)(255 - tid); scal[1] = s_ex; scal[2] = h;
            }
        }
        __syncthreads();
        prefix  |= (uint64_t)scal[0] << shift;
        kmask   |= (uint64_t)0xFFu << shift;
        cnt_gt  += scal[1];
        rank_rem -= scal[1];
        solved = (cnt_gt + scal[2] <= CAPC);
        __syncthreads();
    }

    // ---- compact candidates ----
    if (tid == 0) scal[3] = 0;
    __syncthreads();
    #pragma unroll
    for (int j = 0; j < 8; ++j) {
        bool valid = (j < 7 || tid < (N2 - 7 * NT2));
        bool pred = valid && ((kk[j] & kmask) >= prefix);
        unsigned long long m = __ballot(pred);
        uint32_t cnt = (uint32_t)__popcll(m);
        uint32_t before = (uint32_t)__popcll(m & ((1ull << lane) - 1ull));
        uint32_t sbase = 0;
        if (lane == 0 && cnt) sbase = atomicAdd(&scal[3], cnt);
        sbase = (uint32_t)__shfl((int)sbase, 0);
        if (pred) {
            uint32_t slot = sbase + before;
            if (slot < CAPC) ck[slot] = kk[j];
        }
    }
    __syncthreads();
    const uint32_t ct = scal[3];

    // ---- rank sort + decode + epilogue ----
    if (tid < (int)ct) {
        uint64_t mk = ck[tid];
        uint32_t rank = 0;
        for (uint32_t j = 0; j < ct; ++j)
            rank += (ck[j] > mk) ? 1u : 0u;
        if (rank < KTOP) {
            uint32_t m  = (uint32_t)(mk >> 21);
            uint32_t vb = (m & 0x80000000u) ? (m ^ 0x80000000u) : ~m;
            float sc = __uint_as_float(vb);
            uint32_t low = (~(uint32_t)mk) & 0x1FFFFFu;
            uint32_t cls = low >> 14;
            int spatial  = (int)(low & 0x3FFFu);
            float ysf = (float)(spatial >> 7);
            float xsf = (float)(spatial & (Wdim - 1));
            float rx = reg[((size_t)b * 2 + 0) * HW + spatial];
            float ry = reg[((size_t)b * 2 + 1) * HW + spatial];
            float ww = wh [((size_t)b * 2 + 0) * HW + spatial];
            float hh = wh [((size_t)b * 2 + 1) * HW + spatial];
            float xb = xsf + rx, yb = ysf + ry;
            float* o = out + ((size_t)b * KTOP + rank) * 6;
            o[0] = xb - ww * 0.5f;
            o[1] = yb - hh * 0.5f;
            o[2] = xb + ww * 0.5f;
            o[3] = yb + hh * 0.5f;
            o[4] = sc;
            o[5] = (float)cls;
        }
    }
}

extern "C" void kernel_launch(void* const* d_in, const int* in_sizes, int n_in,
                              void* d_out, int out_size, void* d_ws, size_t ws_size,
                              hipStream_t stream)
{
    const float* heat = (const float*)d_in[0];
    const float* wh   = (const float*)d_in[1];
    const float* reg  = (const float*)d_in[2];
    float* out = (float*)d_out;

    uint64_t* keys_ws = (uint64_t*)d_ws;   // 16*80*100*8B = 1.024 MB

    nms_topk_kernel<<<Bdim * Cdim, NT1, 0, stream>>>(heat, keys_ws);
    global_topk_kernel<<<Bdim, NT2, 0, stream>>>(keys_ws, wh, reg, out);
}